// Round 6
// baseline (169.767 us; speedup 1.0000x reference)
//
#include <hip/hip_runtime.h>
#include <math.h>

// Problem constants (from reference setup_inputs)
#define BATCH 64
#define NPATCH 784
#define DIM 768
#define KSEL 392          // int(784 * 0.5)
#define SIDE 28
#define HWDIM 448
#define NPIX (HWDIM*HWDIM)     // 200704
#define PARTS 49               // partial-reduction blocks per batch for COG
#define PIX_PER_PART (NPIX/PARTS)  // 4096
#define GSPLIT 4               // selection roles per batch (last 4 arrivals)
#define IPB 196                // elements per selection role (784/4)

typedef float f4v __attribute__((ext_vector_type(4)));
typedef unsigned long long u64;

// ---------------------------------------------------------------------------
// Fused kernel: COG partial sums + (last-4-arrivals-per-batch) selection.
//
// Each of the 49 blocks per batch computes its partial in fixed order (f64
// tree, f32 per-element product rounding emulating numpy), publishes it with
// a release atomicAdd on cnt[b]. The 4 blocks observing prev in {45,46,47,48}
// take selection role g = prev-45, acquire-spin until cnt[b]==49 (all
// partials visible), then run the selection for their 196 elements. The
// selection computation depends only on (b, g, part[]) -> deterministic
// regardless of which physical blocks draw the roles. cnt[] is zeroed by a
// memset node each call, so correctness call and every replay are identical.
// ---------------------------------------------------------------------------
__global__ __launch_bounds__(256) void cog_select(
        const float* __restrict__ ld,      // [64, 1, 448, 448]
        const float* __restrict__ scores,  // [64, 784]
        double* __restrict__ part,         // ws: [64*49*3]
        unsigned* __restrict__ cnt,        // ws: [64], zeroed each call
        int* __restrict__ sel) {           // ws: [64*392]
    const int blk = blockIdx.x;
    const int b = blk / PARTS;
    const int p = blk % PARTS;
    const int t = threadIdx.x;
    const int wid = t >> 6;
    const int lane = t & 63;

    __shared__ alignas(16) float lin[HWDIM];   // f32(e/447.0) == np.linspace(0,1,448)
    for (int e = t; e < HWDIM; e += 256) lin[e] = (float)((double)e / 447.0);
    __syncthreads();

    // ---- partial sums over this block's 4096 pixels (identical math to R5) ----
    {
        const float* base = ld + (size_t)b * NPIX + (size_t)p * PIX_PER_PART;
        double s = 0.0, sy = 0.0, sx = 0.0;
        #pragma unroll
        for (int r = 0; r < 4; ++r) {
            const int f4 = r * 256 + t;                 // 0..1023
            const int pix = p * PIX_PER_PART + f4 * 4;  // within-batch pixel idx
            const f4v v = reinterpret_cast<const f4v*>(base)[f4];
            const int i = pix / HWDIM;
            const int j = pix - i * HWDIM;              // j % 4 == 0
            const float yf = lin[i];
            const f4v xq = *reinterpret_cast<const f4v*>(&lin[j]);
            s  += (double)v.x + (double)v.y + (double)v.z + (double)v.w;
            sy += (double)__fmul_rn(v.x, yf) + (double)__fmul_rn(v.y, yf)
                + (double)__fmul_rn(v.z, yf) + (double)__fmul_rn(v.w, yf);
            sx += (double)__fmul_rn(v.x, xq.x) + (double)__fmul_rn(v.y, xq.y)
                + (double)__fmul_rn(v.z, xq.z) + (double)__fmul_rn(v.w, xq.w);
        }

        __shared__ double red[3 * 256];
        red[t] = s; red[256 + t] = sy; red[512 + t] = sx;
        __syncthreads();
        for (int off = 128; off > 0; off >>= 1) {
            if (t < off) {
                red[t]       += red[t + off];
                red[256 + t] += red[256 + t + off];
                red[512 + t] += red[512 + t + off];
            }
            __syncthreads();
        }
        if (t == 0) {
            double* dst = part + (size_t)(b * PARTS + p) * 3;
            dst[0] = red[0]; dst[1] = red[256]; dst[2] = red[512];
        }
    }

    // ---- arrival: last 4 blocks of this batch take selection roles ----
    __shared__ int sg;
    if (t == 0) {
        // release: orders this block's part[] store before the add
        const unsigned prev = __hip_atomic_fetch_add(&cnt[b], 1u,
                                  __ATOMIC_ACQ_REL, __HIP_MEMORY_SCOPE_AGENT);
        sg = (int)prev - (PARTS - GSPLIT);   // >=0 -> selection role g in 0..3
    }
    __syncthreads();
    const int g = sg;
    if (g < 0) return;

    // acquire-spin until all 49 partials of batch b are published.
    // Safe: <=256 spinners across the grid vs ~2048 resident slots, and
    // producers are plain blocks that always make progress.
    while (__hip_atomic_load(&cnt[b], __ATOMIC_ACQUIRE, __HIP_MEMORY_SCOPE_AGENT)
           < (unsigned)PARTS) {
        __builtin_amdgcn_s_sleep(8);
    }
    __syncthreads();

    // ---- COG combine (deterministic fixed-order tree over 49 partials;
    //      identical code+data in all 4 role-blocks of a batch) ----
    __shared__ double sd[3][64];
    __shared__ float scog[2];
    if (t < 64) {
        if (t < PARTS) {
            const double* src = part + (size_t)(b * PARTS + t) * 3;
            sd[0][t] = src[0]; sd[1][t] = src[1]; sd[2][t] = src[2];
        } else {
            sd[0][t] = 0.0; sd[1][t] = 0.0; sd[2][t] = 0.0;
        }
    }
    __syncthreads();
    for (int off = 32; off > 0; off >>= 1) {
        if (t < off) {
            sd[0][t] += sd[0][t + off];
            sd[1][t] += sd[1][t + off];
            sd[2][t] += sd[2][t + off];
        }
        __syncthreads();
    }
    if (t == 0) {
        // reference: total = sum + 1e-6 (f32); cog = num / total (f32)
        const float total = __fadd_rn((float)sd[0][0], 1e-6f);
        scog[0] = __fdiv_rn((float)sd[1][0], total);   // cy
        scog[1] = __fdiv_rn((float)sd[2][0], total);   // cx
    }
    __syncthreads();
    const float cy = scog[0];
    const float cx = scog[1];

    // ---- weighted scores -> packed sort keys + ballot above-mask ----
    //   key(n) = (bits(w_n) << 10) | (1023 - n): w_n >= 0 so bit order ==
    //   value order; low bits reproduce lax.top_k's lower-index-first ties.
    __shared__ alignas(16) u64 skey[NPATCH];
    __shared__ u64 ajm[16];                 // 784-bit above-threshold mask
    #pragma unroll
    for (int pass = 0; pass < 4; ++pass) {
        const int n = pass * 256 + t;
        const bool valid = n < NPATCH;
        float wt = 0.0f;
        if (valid) {
            const int r = n / SIDE;
            const int c = n - r * SIDE;
            // linspace(0,1,28)[i] = f32(i/27)
            const float gy = (float)((double)r / 27.0);
            const float gx = (float)((double)c / 27.0);
            const float dy = gy - cy;
            const float dx = gx - cx;
            // numpy: dy2, dx2 rounded separately, then summed (no FMA)
            const float dy2 = __fmul_rn(dy, dy);
            const float dx2 = __fmul_rn(dx, dx);
            const float d2 = __fadd_rn(dy2, dx2);
            // -d2/0.125 == -8*d2 exactly; exp in f64 then round (<=0.5 ulp)
            const float w = (float)exp((double)(-8.0f * d2));
            wt = __fmul_rn(scores[(size_t)b * NPATCH + n], w);
            skey[n] = ((u64)__float_as_uint(wt) << 10) | (u64)(1023 - n);
        }
        const u64 m = __ballot(valid && (wt > 0.3f));
        if (lane == 0) ajm[pass * 4 + wid] = m;     // bits for n in [64q, 64q+64)
    }
    __syncthreads();

    // ---- rank my 196 elements' worth (this role's slice) ----
    //   r_all = #{j: key_j > key_i} is the stable descending top-k slot; in
    //   the combined path a below-threshold element's slot count + r_below
    //   equals r_all, and an above-threshold element's slot is the prefix
    //   popcount r_pre over the above-mask.
    const int i = g * IPB + t;
    if (t < IPB) {
        const u64 ki = skey[i];
        int r0 = 0, r1 = 0, r2 = 0, r3 = 0;
        #pragma unroll 4
        for (int j = 0; j < NPATCH; j += 4) {
            r0 += skey[j + 0] > ki;
            r1 += skey[j + 1] > ki;
            r2 += skey[j + 2] > ki;
            r3 += skey[j + 3] > ki;
        }
        const int r_all = (r0 + r1) + (r2 + r3);

        int count = 0;
        #pragma unroll
        for (int q = 0; q < 16; ++q) count += __popcll(ajm[q]);

        const int qi = i >> 6;
        const bool above_i = (ajm[qi] >> (u64)(i & 63)) & 1ull;
        int r_pre = 0;
        for (int q = 0; q < qi; ++q) r_pre += __popcll(ajm[q]);
        r_pre += __popcll(ajm[qi] & ((1ull << (u64)(i & 63)) - 1ull));

        const bool use_topk = (count == 0) || (count >= KSEL);
        const int dst = (!use_topk && above_i) ? r_pre : r_all;
        if (dst < KSEL) sel[(size_t)b * KSEL + dst] = i;
    }
}

// ---------------------------------------------------------------------------
// Gather + add. 256 threads = 4 waves; one row per wave, 3 float4 per lane,
// loads issued before adds. Cached loads (pos stays L2-resident); nontemporal
// stores keep the write-once output from evicting it.
// ---------------------------------------------------------------------------
__global__ __launch_bounds__(256) void gather_add(const float* __restrict__ magno,
                                                  const float* __restrict__ pos,
                                                  const int* __restrict__ sel,
                                                  float* __restrict__ out) {
    const int wid = threadIdx.x >> 6;
    const int lane = threadIdx.x & 63;
    const int row = blockIdx.x * 4 + wid;   // 0 .. BATCH*KSEL-1
    const int b = row / KSEL;
    const int s = sel[row];

    const f4v* src = reinterpret_cast<const f4v*>(magno + ((size_t)b * NPATCH + s) * DIM);
    const f4v* pp  = reinterpret_cast<const f4v*>(pos + (size_t)(s + 1) * DIM);
    f4v* dst = reinterpret_cast<f4v*>(out + (size_t)row * DIM);

    const f4v a0 = src[lane], a1 = src[64 + lane], a2 = src[128 + lane];
    const f4v p0 = pp[lane],  p1 = pp[64 + lane],  p2 = pp[128 + lane];
    __builtin_nontemporal_store(a0 + p0, dst + lane);
    __builtin_nontemporal_store(a1 + p1, dst + 64 + lane);
    __builtin_nontemporal_store(a2 + p2, dst + 128 + lane);
}

extern "C" void kernel_launch(void* const* d_in, const int* in_sizes, int n_in,
                              void* d_out, int out_size, void* d_ws, size_t ws_size,
                              hipStream_t stream) {
    const float* magno  = (const float*)d_in[0];  // [64, 784, 768]
    const float* vit    = (const float*)d_in[1];  // [1, 785, 768]
    const float* scores = (const float*)d_in[2];  // [64, 784]
    const float* ld     = (const float*)d_in[3];  // [64, 1, 448, 448]
    float* out = (float*)d_out;                   // [64, 392, 768]

    // workspace layout
    double*   partials = (double*)d_ws;           // 64*49*3 doubles
    int*      sel = (int*)((char*)d_ws + (size_t)BATCH * PARTS * 3 * sizeof(double));
    unsigned* cnt = (unsigned*)((char*)sel + (size_t)BATCH * KSEL * sizeof(int));

    hipMemsetAsync(cnt, 0, BATCH * sizeof(unsigned), stream);
    cog_select<<<dim3(BATCH * PARTS), dim3(256), 0, stream>>>(ld, scores, partials, cnt, sel);
    gather_add<<<dim3(BATCH * KSEL / 4), dim3(256), 0, stream>>>(magno, vit, sel, out);
}

// Round 7
// 53.359 us; speedup vs baseline: 3.1816x; 3.1816x over previous
//
#include <hip/hip_runtime.h>
#include <math.h>

// Problem constants (from reference setup_inputs)
#define BATCH 64
#define NPATCH 784
#define DIM 768
#define KSEL 392          // int(784 * 0.5)
#define SIDE 28
#define HWDIM 448
#define NPIX (HWDIM*HWDIM)     // 200704
#define PARTS 49               // blocks per batch for COG partial reduction
#define PIX_PER_PART (NPIX/PARTS)  // 4096
#define GSPLIT 4               // selection blocks per batch
#define IPB 196                // elements per selection block (784/4)

typedef float f4v __attribute__((ext_vector_type(4)));
typedef unsigned long long u64;

// ---------------------------------------------------------------------------
// Kernel 1: partial COG sums per (batch, part). Per-element f32 products
// emulate numpy rounding; f64 accumulation in a fixed deterministic order
// (serial per thread, then wave shuffle butterfly, then 4-way serial).
// All f64 divisions hoisted into a 448-entry LDS linspace table.
// ---------------------------------------------------------------------------
__global__ __launch_bounds__(256) void cog_partial(const float* __restrict__ ld,
                                                   double* __restrict__ part) {
    const int blk = blockIdx.x;
    const int b = blk / PARTS;
    const int p = blk % PARTS;
    const int t = threadIdx.x;
    const int wid = t >> 6;
    const int lane = t & 63;

    __shared__ alignas(16) float lin[HWDIM];   // f32(e/447.0) == np.linspace(0,1,448)
    for (int e = t; e < HWDIM; e += 256) lin[e] = (float)((double)e / 447.0);
    __syncthreads();

    const float* base = ld + (size_t)b * NPIX + (size_t)p * PIX_PER_PART;
    double s = 0.0, sy = 0.0, sx = 0.0;

    // 4096 pixels per part = 1024 float4; 256 threads x 4 float4 each.
    // 448 % 4 == 0 so each float4 stays within one image row, and j % 4 == 0
    // so the x-coordinate quad is one aligned LDS float4 read.
    #pragma unroll
    for (int r = 0; r < 4; ++r) {
        const int f4 = r * 256 + t;                 // 0..1023
        const int pix = p * PIX_PER_PART + f4 * 4;  // within-batch pixel idx
        const f4v v = reinterpret_cast<const f4v*>(base)[f4];
        const int i = pix / HWDIM;
        const int j = pix - i * HWDIM;
        const float yf = lin[i];
        const f4v xq = *reinterpret_cast<const f4v*>(&lin[j]);
        s  += (double)v.x + (double)v.y + (double)v.z + (double)v.w;
        sy += (double)__fmul_rn(v.x, yf) + (double)__fmul_rn(v.y, yf)
            + (double)__fmul_rn(v.z, yf) + (double)__fmul_rn(v.w, yf);
        sx += (double)__fmul_rn(v.x, xq.x) + (double)__fmul_rn(v.y, xq.y)
            + (double)__fmul_rn(v.z, xq.z) + (double)__fmul_rn(v.w, xq.w);
    }

    // in-wave butterfly reduce (fixed order -> deterministic)
    #pragma unroll
    for (int off = 32; off > 0; off >>= 1) {
        s  += __shfl_down(s, off);
        sy += __shfl_down(sy, off);
        sx += __shfl_down(sx, off);
    }

    __shared__ double red[3][4];
    if (lane == 0) { red[0][wid] = s; red[1][wid] = sy; red[2][wid] = sx; }
    __syncthreads();
    if (t == 0) {
        double* dst = part + (size_t)(b * PARTS + p) * 3;
        dst[0] = (red[0][0] + red[0][1]) + (red[0][2] + red[0][3]);
        dst[1] = (red[1][0] + red[1][1]) + (red[1][2] + red[1][3]);
        dst[2] = (red[2][0] + red[2][1]) + (red[2][2] + red[2][3]);
    }
}

// ---------------------------------------------------------------------------
// Kernel 2: fused COG-combine + selection via packed 64-bit sort keys.
//   key(n) = (bits(w_n) << 10) | (1023 - n)   (w_n >= 0, so bit order == value
//   order; low bits break ties exactly like lax.top_k: lower index ranks first)
// Facts used (proven from the reference semantics):
//   - r_all = #{j: key_j > key_i} is the stable descending-top-k slot.
//   - In the combined (0 < count < k) path, a BELOW-threshold element's slot
//     count + r_below == r_all (every above-threshold j outranks every
//     below-threshold i, strictly).
//   - An ABOVE-threshold element's slot is r_pre = #{above j < i}: a prefix
//     popcount over the 784-bit above-mask (built with wave ballots).
// ---------------------------------------------------------------------------
__global__ __launch_bounds__(256) void select_k(const float* __restrict__ scores,
                                                const double* __restrict__ part,
                                                int* __restrict__ sel) {
    const int blk = blockIdx.x;
    const int b = blk / GSPLIT;
    const int g = blk % GSPLIT;
    const int t = threadIdx.x;
    const int wid = t >> 6;
    const int lane = t & 63;

    __shared__ double sd[3][64];
    __shared__ float scog[2];
    __shared__ alignas(16) u64 skey[NPATCH];
    __shared__ u64 ajm[16];                 // 784-bit above-threshold mask (padded)

    // --- COG combine (deterministic fixed-order tree over 49 partials;
    //     identical code+data in all 4 blocks of a batch) ---
    if (t < 64) {
        if (t < PARTS) {
            const double* src = part + (size_t)(b * PARTS + t) * 3;
            sd[0][t] = src[0]; sd[1][t] = src[1]; sd[2][t] = src[2];
        } else {
            sd[0][t] = 0.0; sd[1][t] = 0.0; sd[2][t] = 0.0;
        }
    }
    __syncthreads();
    for (int off = 32; off > 0; off >>= 1) {
        if (t < off) {
            sd[0][t] += sd[0][t + off];
            sd[1][t] += sd[1][t + off];
            sd[2][t] += sd[2][t + off];
        }
        __syncthreads();
    }
    if (t == 0) {
        // reference: total = sum + 1e-6 (f32); cog = num / total (f32)
        const float total = __fadd_rn((float)sd[0][0], 1e-6f);
        scog[0] = __fdiv_rn((float)sd[1][0], total);   // cy
        scog[1] = __fdiv_rn((float)sd[2][0], total);   // cx
    }
    __syncthreads();
    const float cy = scog[0];
    const float cx = scog[1];

    // --- weighted scores -> keys + ballot above-mask ---
    #pragma unroll
    for (int pass = 0; pass < 4; ++pass) {
        const int n = pass * 256 + t;
        const bool valid = n < NPATCH;
        float wt = 0.0f;
        if (valid) {
            const int r = n / SIDE;
            const int c = n - r * SIDE;
            // linspace(0,1,28)[i] = f32(i/27)
            const float gy = (float)((double)r / 27.0);
            const float gx = (float)((double)c / 27.0);
            const float dy = gy - cy;
            const float dx = gx - cx;
            // numpy: dy2, dx2 rounded separately, then summed (no FMA)
            const float dy2 = __fmul_rn(dy, dy);
            const float dx2 = __fmul_rn(dx, dx);
            const float d2 = __fadd_rn(dy2, dx2);
            // -d2/0.125 == -8*d2 exactly; exp in f64 then round (<=0.5 ulp)
            const float w = (float)exp((double)(-8.0f * d2));
            wt = __fmul_rn(scores[(size_t)b * NPATCH + n], w);
            skey[n] = ((u64)__float_as_uint(wt) << 10) | (u64)(1023 - n);
        }
        const u64 m = __ballot(valid && (wt > 0.3f));
        if (lane == 0) ajm[pass * 4 + wid] = m;     // bits for n in [64q, 64q+64)
    }
    __syncthreads();

    // --- rank my element ---
    const int i = g * IPB + t;
    if (t < IPB) {
        const u64 ki = skey[i];
        int r0 = 0, r1 = 0, r2 = 0, r3 = 0;
        #pragma unroll 4
        for (int j = 0; j < NPATCH; j += 4) {
            r0 += skey[j + 0] > ki;
            r1 += skey[j + 1] > ki;
            r2 += skey[j + 2] > ki;
            r3 += skey[j + 3] > ki;
        }
        const int r_all = (r0 + r1) + (r2 + r3);

        int count = 0;
        #pragma unroll
        for (int q = 0; q < 16; ++q) count += __popcll(ajm[q]);

        const int qi = i >> 6;
        const bool above_i = (ajm[qi] >> (u64)(i & 63)) & 1ull;
        int r_pre = 0;
        for (int q = 0; q < qi; ++q) r_pre += __popcll(ajm[q]);
        r_pre += __popcll(ajm[qi] & ((1ull << (u64)(i & 63)) - 1ull));

        const bool use_topk = (count == 0) || (count >= KSEL);
        const int dst = (!use_topk && above_i) ? r_pre : r_all;
        if (dst < KSEL) sel[(size_t)b * KSEL + dst] = i;
    }
}

// ---------------------------------------------------------------------------
// Kernel 3: gather + add. 256 threads = 4 waves; TWO rows per wave with all
// 12 loads issued before the adds (MLP), 3 float4 per lane per row. Cached
// loads (pos stays L2-resident); nontemporal stores for the write-once output.
// ---------------------------------------------------------------------------
__global__ __launch_bounds__(256) void gather_add(const float* __restrict__ magno,
                                                  const float* __restrict__ pos,
                                                  const int* __restrict__ sel,
                                                  float* __restrict__ out) {
    const int wid = threadIdx.x >> 6;
    const int lane = threadIdx.x & 63;
    const int w = blockIdx.x * 4 + wid;     // wave id: 0 .. BATCH*KSEL/2 - 1
    const int row0 = w * 2;
    const int row1 = row0 + 1;
    const int b0 = row0 / KSEL;
    const int b1 = row1 / KSEL;
    const int s0 = sel[row0];
    const int s1 = sel[row1];

    const f4v* src0 = reinterpret_cast<const f4v*>(magno + ((size_t)b0 * NPATCH + s0) * DIM);
    const f4v* src1 = reinterpret_cast<const f4v*>(magno + ((size_t)b1 * NPATCH + s1) * DIM);
    const f4v* pp0  = reinterpret_cast<const f4v*>(pos + (size_t)(s0 + 1) * DIM);
    const f4v* pp1  = reinterpret_cast<const f4v*>(pos + (size_t)(s1 + 1) * DIM);
    f4v* dst0 = reinterpret_cast<f4v*>(out + (size_t)row0 * DIM);
    f4v* dst1 = reinterpret_cast<f4v*>(out + (size_t)row1 * DIM);

    const f4v a0 = src0[lane], a1 = src0[64 + lane], a2 = src0[128 + lane];
    const f4v c0 = src1[lane], c1 = src1[64 + lane], c2 = src1[128 + lane];
    const f4v p0 = pp0[lane],  p1 = pp0[64 + lane],  p2 = pp0[128 + lane];
    const f4v q0 = pp1[lane],  q1 = pp1[64 + lane],  q2 = pp1[128 + lane];

    __builtin_nontemporal_store(a0 + p0, dst0 + lane);
    __builtin_nontemporal_store(a1 + p1, dst0 + 64 + lane);
    __builtin_nontemporal_store(a2 + p2, dst0 + 128 + lane);
    __builtin_nontemporal_store(c0 + q0, dst1 + lane);
    __builtin_nontemporal_store(c1 + q1, dst1 + 64 + lane);
    __builtin_nontemporal_store(c2 + q2, dst1 + 128 + lane);
}

extern "C" void kernel_launch(void* const* d_in, const int* in_sizes, int n_in,
                              void* d_out, int out_size, void* d_ws, size_t ws_size,
                              hipStream_t stream) {
    const float* magno  = (const float*)d_in[0];  // [64, 784, 768]
    const float* vit    = (const float*)d_in[1];  // [1, 785, 768]
    const float* scores = (const float*)d_in[2];  // [64, 784]
    const float* ld     = (const float*)d_in[3];  // [64, 1, 448, 448]
    float* out = (float*)d_out;                   // [64, 392, 768]

    // workspace layout
    double* partials = (double*)d_ws;             // 64*49*3 doubles
    int*    sel = (int*)((char*)d_ws + (size_t)BATCH * PARTS * 3 * sizeof(double));

    cog_partial<<<dim3(BATCH * PARTS), dim3(256), 0, stream>>>(ld, partials);
    select_k<<<dim3(BATCH * GSPLIT), dim3(256), 0, stream>>>(scores, partials, sel);
    gather_add<<<dim3(BATCH * KSEL / 8), dim3(256), 0, stream>>>(magno, vit, sel, out);
}